// Round 23
// baseline (210.073 us; speedup 1.0000x reference)
//
#include <hip/hip_runtime.h>
#include <hip/hip_bf16.h>

#define C_DIM 128
#define TWO_C 256
#define FC    32
#define T_DIM 512
#define HB    128
#define NMAX  32768
#define PREP_TOT (32768 + 32768 + 4096 + 1024)

typedef unsigned int   u32;
typedef unsigned short u16;
typedef unsigned long long u64;
typedef short bf16x8 __attribute__((ext_vector_type(8)));
typedef float f32x4  __attribute__((ext_vector_type(4)));
typedef int   i32x4  __attribute__((ext_vector_type(4)));
typedef u32   u32x4  __attribute__((ext_vector_type(4)));

__device__ __forceinline__ float fast_rcp(float x) {
    return __builtin_amdgcn_rcpf(x);          // v_rcp_f32, ~1 ULP
}
// gelu via A&S 7.1.27 rational erf (|eps_erf| <= 5e-4), 1/sqrt2 folded into coeffs.
__device__ __forceinline__ float gelu_f(float x) {
    float a = fabsf(x);
    float p = 1.0f + a * (0.19685352f + a * (0.11519450f +
              a * (3.4364302e-4f + a * 0.019527027f)));
    float d  = fast_rcp(p);
    float d2 = d * d;
    float d4 = d2 * d2;
    float s = 0.5f * x;
    return s + s * copysignf(1.0f - d4, x);
}
__device__ __forceinline__ u32 f2bf_bits(float x) {
    u32 u = __float_as_uint(x);
    return (u + 0x7fffu + ((u >> 16) & 1u)) >> 16;   // RNE f32->bf16
}
__device__ __forceinline__ u32 pack_bf2(float lo, float hi) {
    __hip_bfloat162 p = __float22bfloat162_rn(make_float2(lo, hi));  // v_cvt_pk_bf16_f32
    u32 r; __builtin_memcpy(&r, &p, 4); return r;
}
__device__ __forceinline__ float bf2f(u16 v) {
    return __uint_as_float((u32)v << 16);
}
// paired-channel h layout: channel c -> u16 index (c>>5)*32 + (c&15)*2 + ((c>>4)&1)
__device__ __forceinline__ int hperm(int c) {
    return ((c >> 5) << 5) + ((c & 15) << 1) + ((c >> 4) & 1);
}

// ---------- k_front: grid-partitioned fusion of independent prologue work ----------
__global__ __launch_bounds__(256) void k_front(
        const float* __restrict__ t,
        const float* __restrict__ tw1, const float* __restrict__ tb1,
        const float* __restrict__ tw2, const float* __restrict__ tb2,
        const float* __restrict__ mw1, const float* __restrict__ mw2,
        const float* __restrict__ kw3, const float* __restrict__ kw2,
        float* __restrict__ tm1, float* __restrict__ tm2,
        u16* __restrict__ w1f, u16* __restrict__ w2f,
        u16* __restrict__ w3f, u16* __restrict__ w2kf,
        float* __restrict__ xbuf,
        int N, int B, int nbPrep, int nbXb) {
    int bid = blockIdx.x, tid = threadIdx.x;

    if (bid < 2 * B) {
        // ---- tmod ----
        int y = bid >= B;
        int b = y ? bid - B : bid;
        const float* twp = y ? tw2 : tw1;
        const float* tbp = y ? tb2 : tb1;
        float*       tmp = y ? tm2 : tm1;
        __shared__ float gt[T_DIM];
        for (int k = tid; k < T_DIM; k += 256)
            gt[k] = gelu_f(t[(size_t)b * T_DIM + k]);
        __syncthreads();
        float acc = tbp[tid];
        for (int k = 0; k < T_DIM; ++k)
            acc += gt[k] * twp[(size_t)k * TWO_C + tid];
        tmp[(size_t)b * TWO_C + tid] = acc;
        return;
    }
    bid -= 2 * B;

    if (bid < nbPrep) {
        int tt = bid * 256 + tid;
        if (tt < 32768) {            // w1f: [nt16][ks4][64][8], W = mw1 [128][256]
            int j = tt & 7, l = (tt >> 3) & 63, f = tt >> 9;
            int ks = f & 3, nt = f >> 2;
            int k = ks * 32 + ((l >> 4) << 3) + j, n = nt * 16 + (l & 15);
            w1f[tt] = (u16)f2bf_bits(mw1[(size_t)k * TWO_C + n]);
        } else if (tt < 65536) {     // w2f: [nt8][ks8][64][8], W = mw2 [256][128]
            int t2 = tt - 32768;
            int j = t2 & 7, l = (t2 >> 3) & 63, f = t2 >> 9;
            int ks = f & 7, nt = f >> 3;
            int k = ks * 32 + ((l >> 4) << 3) + j, n = nt * 16 + (l & 15);
            w2f[t2] = (u16)f2bf_bits(mw2[(size_t)k * C_DIM + n]);
        } else if (tt < 69632) {     // w3f: k permuted by pi
            int t3 = tt - 65536;
            int j = t3 & 7, l = (t3 >> 3) & 63, nt = t3 >> 9;
            int kk = ((l >> 4) << 3) + j;
            int k = (kk >> 1) + ((kk & 1) << 4);
            int n = nt * 16 + (l & 15);
            w3f[t3] = (u16)f2bf_bits(kw3[(size_t)k * C_DIM + n]);
        } else if (tt < PREP_TOT) {  // w2kf
            int t4 = tt - 69632;
            int j = t4 & 7, l = (t4 >> 3) & 63, nt = t4 >> 9;
            int kk = ((l >> 4) << 3) + j;
            int n = nt * 16 + (l & 15);
            w2kf[t4] = (u16)f2bf_bits(kw2[(size_t)kk * FC + n]);
        }
        return;
    }
    bid -= nbPrep;

    if (bid < nbXb) {
        size_t i = ((size_t)bid * 256 + tid) * 4;
        if (i < (size_t)N * C_DIM)
            *(float4*)(xbuf + i) = make_float4(0.f, 0.f, 0.f, 0.f);
        return;
    }
}

// ---------- k_mod2: LN1+modulate, 2 rows/block (bitwise k_mod numerics) ----------
__global__ __launch_bounds__(256) void k_mod2(
        const float* __restrict__ feats,
        const float* __restrict__ lns, const float* __restrict__ lnb,
        const float* __restrict__ tm,
        u16* __restrict__ h_mod, int q, int N) {
    __shared__ float red2[2][4];
    int tid = threadIdx.x;
    int gi = tid >> 7, c = tid & 127;
    int n = 2 * blockIdx.x + gi;
    bool live = (n < N);
    size_t o = (size_t)n * C_DIM + c;
    float v = live ? feats[o] : 0.f;           // dummy rows participate in syncs
    float s1 = v, s2 = v * v;
#pragma unroll
    for (int off = 32; off > 0; off >>= 1) {
        s1 += __shfl_down(s1, off);
        s2 += __shfl_down(s2, off);
    }
    if ((c & 63) == 0) {
        red2[gi][(c >> 6) * 2] = s1;
        red2[gi][(c >> 6) * 2 + 1] = s2;
    }
    __syncthreads();
    if (n == N) { h_mod[(size_t)N * C_DIM + c] = 0; return; }
    if (!live) return;
    float mean = (red2[gi][0] + red2[gi][2]) * (1.0f / C_DIM);
    float ex2  = (red2[gi][1] + red2[gi][3]) * (1.0f / C_DIM);
    float r    = rsqrtf(ex2 - mean * mean + 1e-5f);
    int b = n / q;
    float scale = tm[(size_t)b * TWO_C + c];
    float shift = tm[(size_t)b * TWO_C + C_DIM + c];
    float h = (v - mean) * r * lns[c] + lnb[c];
    float res = h * (1.0f + scale) + shift;
    h_mod[(size_t)n * C_DIM + hperm(c)] = (u16)f2bf_bits(res);
}

// ---------- pass 1: per-block LDS histogram (packed u16 pairs), no global atomics ----------
__global__ __launch_bounds__(1024) void k_hist_lds(const int* __restrict__ dst,
                                                   u16* __restrict__ histB,
                                                   int N, int E) {
    __shared__ u32 lh[NMAX / 2];               // 64 KB: counts for dst pairs (2i, 2i+1)
    int tid = threadIdx.x, b = blockIdx.x;
    int half = N >> 1;
    for (int i = tid; i < half; i += 1024) lh[i] = 0;
    __syncthreads();
    int e0 = (int)((size_t)b * E / HB), e1 = (int)((size_t)(b + 1) * E / HB);
    for (int e = e0 + tid; e < e1; e += 1024) {
        int d = dst[e];
        atomicAdd(&lh[d >> 1], (d & 1) ? 0x10000u : 1u);
    }
    __syncthreads();
    u16* outp = histB + (size_t)b * N;
    for (int i = tid; i < half; i += 1024) {
        u32 v = lh[i];
        outp[2 * i]     = (u16)(v & 0xffffu);
        outp[2 * i + 1] = (u16)(v >> 16);
    }
}

// ---------- scan phase A: per-block reduction over block-histogram sums ----------
__global__ __launch_bounds__(1024) void k_scan_bsum(const u16* __restrict__ histB,
                                                    u64* __restrict__ bsum, int N) {
    __shared__ u64 red[1024];
    int t = threadIdx.x;
    int idx = blockIdx.x * 1024 + t;
    int v = 0;
    if (idx < N) {
        for (int b = 0; b < HB; ++b) v += histB[(size_t)b * N + idx];
    }
    red[t] = (u64)(u32)v | ((u64)(u32)((v + 15) >> 4) << 32);
    __syncthreads();
#pragma unroll
    for (int off = 512; off > 0; off >>= 1) {
        if (t < off) red[t] += red[t + off];
        __syncthreads();
    }
    if (t == 0) bsum[blockIdx.x] = red[0];
}

// ---------- scan phase B: local scan + per-block base table + tinfo + Ttot ----------
__global__ __launch_bounds__(1024) void k_scan_final(const u16* __restrict__ histB,
                                                     const u64* __restrict__ bsum,
                                                     int* __restrict__ blockBase,
                                                     int4* __restrict__ tinfo,
                                                     int* __restrict__ Ttot,
                                                     int N, int nb) {
    __shared__ u64 tot[1024];
    __shared__ u64 bex;
    int t = threadIdx.x;
    int idx = blockIdx.x * 1024 + t;
    int v = 0;
    if (idx < N) {
        for (int b = 0; b < HB; ++b) v += histB[(size_t)b * N + idx];
    }
    u64 pk = (u64)(u32)v | ((u64)(u32)((v + 15) >> 4) << 32);
    tot[t] = pk;
    if (t == 0) {                              // serial prefix over <=32 block sums
        u64 run = 0, mine = 0;
        for (int i = 0; i < nb; ++i) {
            if (i == (int)blockIdx.x) mine = run;
            run += bsum[i];
        }
        bex = mine;
        if (blockIdx.x == 0) Ttot[0] = (int)(run >> 32);
    }
    __syncthreads();
    for (int off = 1; off < 1024; off <<= 1) {
        u64 a = (t >= off) ? tot[t - off] : 0ull;
        __syncthreads();
        tot[t] += a;
        __syncthreads();
    }
    if (idx >= N) return;
    u64 ex = tot[t] - pk + bex;                // exclusive global prefix
    int rd = (int)(ex & 0xffffffffull);
    int rt = (int)(ex >> 32);
    int run = rd;
    for (int b = 0; b < HB; ++b) {             // per-block segment bases
        blockBase[(size_t)b * N + idx] = run;
        run += histB[(size_t)b * N + idx];
    }
    int nt = (v + 15) >> 4;
    int e = rd + v;
    for (int k = 0; k < nt; ++k)
        tinfo[rt + k] = make_int4(idx, rd + 16 * k, e, 0);
}

// ---------- pass 2: rank via LDS atomic return + base load; 8B record scatter ----------
__global__ __launch_bounds__(1024) void k_sed2(const int* __restrict__ ei,
                                               const float* __restrict__ ea,
                                               const int* __restrict__ blockBase,
                                               uint2* __restrict__ sed2,
                                               int N, int E) {
    __shared__ u32 lh[NMAX / 2];               // 64 KB
    int tid = threadIdx.x, b = blockIdx.x;
    int half = N >> 1;
    for (int i = tid; i < half; i += 1024) lh[i] = 0;
    __syncthreads();
    int e0 = (int)((size_t)b * E / HB), e1 = (int)((size_t)(b + 1) * E / HB);
    const int* dstp = ei + E;
    for (int e = e0 + tid; e < e1; e += 1024) {
        int d = dstp[e];
        u32 old = atomicAdd(&lh[d >> 1], (d & 1) ? 0x10000u : 1u);
        int lrank = (d & 1) ? (int)(old >> 16) : (int)(old & 0xffffu);
        int pos = blockBase[(size_t)b * N + d] + lrank;
        float2 av = ((const float2*)ea)[e];
        uint2 v;
        v.x = pack_bf2(av.x, av.y);
        v.y = (u32)ei[e];
        sed2[pos] = v;
    }
}

// ---------- edge kernel-MLP in SORTED order: nt streaming in/out ----------
__global__ __launch_bounds__(256) void k_edgek2s(
        const uint2* __restrict__ sed2,
        const float* __restrict__ w1, const float* __restrict__ b1,
        const u16* __restrict__ w2kf, const float* __restrict__ b2,
        u32* __restrict__ k2h, int E) {
    int l = threadIdx.x & 63, wv = threadIdx.x >> 6;
    int lr = l & 15, g = l >> 4;
    int wbase = blockIdx.x * 256 + wv * 64;

    bf16x8 wb0 = *(const bf16x8*)(w2kf + (size_t)l * 8);
    bf16x8 wb1 = *(const bf16x8*)(w2kf + (size_t)(64 + l) * 8);
    f32x4 bi0, bi1;
    {
        float v0 = b2[lr], v1 = b2[16 + lr];
        bi0[0] = v0; bi0[1] = v0; bi0[2] = v0; bi0[3] = v0;
        bi1[0] = v1; bi1[1] = v1; bi1[2] = v1; bi1[3] = v1;
    }
    float w1x[8], w1y[8], b1v[8];
#pragma unroll
    for (int j = 0; j < 8; ++j) {
        w1x[j] = w1[8 * g + j];
        w1y[j] = w1[FC + 8 * g + j];
        b1v[j] = b1[8 * g + j];
    }
#pragma unroll
    for (int c = 0; c < 4; ++c) {
        int cb = wbase + 16 * c;
        int pA = cb + lr;
        float ax = 0.f, ay = 0.f;
        if (pA < E) {
            u32 pr = __builtin_nontemporal_load(&sed2[pA].x);
            ax = bf2f((u16)(pr & 0xffffu));
            ay = bf2f((u16)(pr >> 16));
        }
        union { u32 w[4]; bf16x8 v; } au;
#pragma unroll
        for (int m = 0; m < 4; ++m) {
            float v0 = gelu_f(fmaf(ax, w1x[2 * m],     fmaf(ay, w1y[2 * m],     b1v[2 * m])));
            float v1 = gelu_f(fmaf(ax, w1x[2 * m + 1], fmaf(ay, w1y[2 * m + 1], b1v[2 * m + 1])));
            au.w[m] = pack_bf2(v0, v1);
        }
        f32x4 d0 = __builtin_amdgcn_mfma_f32_16x16x32_bf16(au.v, wb0, bi0, 0, 0, 0);
        f32x4 d1 = __builtin_amdgcn_mfma_f32_16x16x32_bf16(au.v, wb1, bi1, 0, 0, 0);
#pragma unroll
        for (int r = 0; r < 4; ++r) {
            int pD = cb + 4 * g + r;
            if (pD < E) {
                u32 pk = pack_bf2(gelu_f(d0[r]), gelu_f(d1[r]));
                __builtin_nontemporal_store(pk, &k2h[(size_t)pD * 16 + lr]);
            }
        }
    }
}

// ---------- conv main: tile-parallel; nt loads for streamed operands ----------
__global__ __launch_bounds__(256, 5) void k_conv4(
        const u16* __restrict__ h_mod,        // (N+1) rows bf16 paired, row N = zeros
        const int* __restrict__ Ttot,
        const int* __restrict__ tinfo,        // {node, p0, end, 0} as 4x i32
        const u32* __restrict__ k2h,          // [E][16] u32, dense sorted
        const uint2* __restrict__ sed2,       // {bf16pair, src}
        const u16* __restrict__ w3f, const float* __restrict__ kb3,
        float* __restrict__ xbuf, int N) {
    int l = threadIdx.x & 63, wv = threadIdx.x >> 6;
    int lr = l & 15, g = l >> 4;

    bf16x8 w3b[8];
#pragma unroll
    for (int nt = 0; nt < 8; ++nt)
        w3b[nt] = *(const bf16x8*)(w3f + ((size_t)nt * 64 + l) * 8);
    float b3c[8];
#pragma unroll
    for (int nt = 0; nt < 8; ++nt) b3c[nt] = kb3[nt * 16 + lr];
    const f32x4 zc = {0.f, 0.f, 0.f, 0.f};
    const u32* h32 = (const u32*)h_mod;

    int T = Ttot[0];
    int nw = gridDim.x * 4;
#pragma unroll 1
    for (int t = blockIdx.x * 4 + wv; t < T; t += nw) {
        i32x4 ti = __builtin_nontemporal_load((const i32x4*)(tinfo + 4 * (size_t)t));
        int n = ti.x, p0 = ti.y, e = ti.z;
        int pa = p0 + lr;
        bf16x8 a = {0, 0, 0, 0, 0, 0, 0, 0};
        if (pa < e) {
            u32x4 av = __builtin_nontemporal_load(
                (const u32x4*)(k2h + (size_t)pa * 16 + g * 4));
            __builtin_memcpy(&a, &av, 16);
        }
        int srcv[4];
#pragma unroll
        for (int r = 0; r < 4; ++r) {
            int pp = p0 + 4 * g + r;
            srcv[r] = (pp < e) ? (int)__builtin_nontemporal_load(&sed2[pp].y) : N;
        }
        const u32* h0p = h32 + (size_t)srcv[0] * 64 + lr;
        const u32* h1p = h32 + (size_t)srcv[1] * 64 + lr;
        const u32* h2p = h32 + (size_t)srcv[2] * 64 + lr;
        const u32* h3p = h32 + (size_t)srcv[3] * 64 + lr;
        float acc[8];
#pragma unroll
        for (int j = 0; j < 4; ++j) {
            f32x4 w0 = __builtin_amdgcn_mfma_f32_16x16x32_bf16(a, w3b[2 * j],     zc, 0, 0, 0);
            f32x4 w1 = __builtin_amdgcn_mfma_f32_16x16x32_bf16(a, w3b[2 * j + 1], zc, 0, 0, 0);
            u32 u0 = h0p[j * 16], u1 = h1p[j * 16], u2 = h2p[j * 16], u3 = h3p[j * 16];
            float l0 = __uint_as_float(u0 << 16), h0 = __uint_as_float(u0 & 0xffff0000u);
            float l1 = __uint_as_float(u1 << 16), h1 = __uint_as_float(u1 & 0xffff0000u);
            float l2 = __uint_as_float(u2 << 16), h2 = __uint_as_float(u2 & 0xffff0000u);
            float l3 = __uint_as_float(u3 << 16), h3 = __uint_as_float(u3 & 0xffff0000u);
            acc[2 * j]     = w0[0] * l0 + w0[1] * l1 + w0[2] * l2 + w0[3] * l3
                           + b3c[2 * j] * (l0 + l1 + l2 + l3);
            acc[2 * j + 1] = w1[0] * h0 + w1[1] * h1 + w1[2] * h2 + w1[3] * h3
                           + b3c[2 * j + 1] * (h0 + h1 + h2 + h3);
        }
#pragma unroll
        for (int nt = 0; nt < 8; ++nt) {
            acc[nt] += __shfl_xor(acc[nt], 16, 64);
            acc[nt] += __shfl_xor(acc[nt], 32, 64);
        }
        float v0 = (g == 0) ? acc[0] : (g == 1) ? acc[2] : (g == 2) ? acc[4] : acc[6];
        float v1 = (g == 0) ? acc[1] : (g == 1) ? acc[3] : (g == 2) ? acc[5] : acc[7];
        float* row = xbuf + (size_t)n * C_DIM + 32 * g + lr;
        atomicAdd(row, v0);
        atomicAdd(row + 16, v1);
    }
}

// ---------- fused FFN (phase 0 replicates k_post BITWISE, 2 rows/pass x 8) ----------
__global__ __launch_bounds__(256) void k_ffn3(const float* __restrict__ feats,
                                              const float* __restrict__ xbuf,
                                              const float* __restrict__ cbias,
                                              const float* __restrict__ normv,
                                              const float* __restrict__ tm2,
                                              const float* __restrict__ ln2s,
                                              const float* __restrict__ ln2b,
                                              const u16* __restrict__ w1f,
                                              const float* __restrict__ b1,
                                              const u16* __restrict__ w2f,
                                              const float* __restrict__ b2,
                                              float* __restrict__ out, int q) {
    __shared__ u16 xmt[2048];
    __shared__ float xt[16][128];
    __shared__ u16 sm[4096];
    __shared__ float red2[2][4];
    int tid = threadIdx.x;
    int n0 = blockIdx.x * 16;

    {
        int gi = tid >> 7, c = tid & 127;
#pragma unroll 1
        for (int it = 0; it < 8; ++it) {
            int rA = 2 * it + gi;
            int n = n0 + rA;
            size_t o = (size_t)n * C_DIM + c;
            float v = feats[o] + (xbuf[o] + cbias[c]) * fast_rcp(normv[n]);
            float s1 = v, s2 = v * v;
#pragma unroll
            for (int off = 32; off > 0; off >>= 1) {
                s1 += __shfl_down(s1, off);
                s2 += __shfl_down(s2, off);
            }
            if ((c & 63) == 0) {
                red2[gi][(c >> 6) * 2] = s1;
                red2[gi][(c >> 6) * 2 + 1] = s2;
            }
            __syncthreads();
            float mean = (red2[gi][0] + red2[gi][2]) * (1.0f / C_DIM);
            float ex2  = (red2[gi][1] + red2[gi][3]) * (1.0f / C_DIM);
            float r    = rsqrtf(ex2 - mean * mean + 1e-5f);
            int b = n / q;
            float scale = tm2[(size_t)b * TWO_C + c];
            float shift = tm2[(size_t)b * TWO_C + C_DIM + c];
            float h = (v - mean) * r * ln2s[c] + ln2b[c];
            float res = h * (1.0f + scale) + shift;
            int byte = rA * 256 + ((c * 2) ^ ((rA & 7) << 4));
            xmt[byte >> 1] = (u16)f2bf_bits(res);
            xt[rA][c] = v;
            __syncthreads();
        }
    }

    int w = tid >> 6, l = tid & 63;
    int lr = l & 15, g = l >> 4;

    bf16x8 a[4];
#pragma unroll
    for (int ks = 0; ks < 4; ++ks) {
        int byte = lr * 256 + ((ks * 64 + g * 16) ^ ((lr & 7) << 4));
        a[ks] = *(const bf16x8*)((const char*)xmt + byte);
    }
    f32x4 acc[4];
#pragma unroll
    for (int i = 0; i < 4; ++i) {
        int nt = w + 4 * i;
        float bv = b1[nt * 16 + lr];
        acc[i][0] = bv; acc[i][1] = bv; acc[i][2] = bv; acc[i][3] = bv;
#pragma unroll
        for (int ks = 0; ks < 4; ++ks) {
            bf16x8 bfr = *(const bf16x8*)(w1f + ((size_t)(nt * 4 + ks) * 64 + l) * 8);
            acc[i] = __builtin_amdgcn_mfma_f32_16x16x32_bf16(a[ks], bfr, acc[i], 0, 0, 0);
        }
    }
#pragma unroll
    for (int i = 0; i < 4; ++i) {
        int nt = w + 4 * i;
#pragma unroll
        for (int r = 0; r < 4; ++r) {
            int row = 4 * g + r, col = nt * 16 + lr;
            int byte = row * 512 + ((col * 2) ^ ((row & 7) << 4));
            sm[byte >> 1] = (u16)f2bf_bits(gelu_f(acc[i][r]));
        }
    }
    __syncthreads();
    f32x4 acc2[2];
#pragma unroll
    for (int i = 0; i < 2; ++i) {
        int nt2 = 2 * w + i;
        float bv = b2[nt2 * 16 + lr];
        acc2[i][0] = bv; acc2[i][1] = bv; acc2[i][2] = bv; acc2[i][3] = bv;
    }
#pragma unroll
    for (int ks = 0; ks < 8; ++ks) {
        int byte = lr * 512 + ((ks * 64 + g * 16) ^ ((lr & 7) << 4));
        bf16x8 a2 = *(const bf16x8*)(sm + (byte >> 1));
#pragma unroll
        for (int i = 0; i < 2; ++i) {
            int nt2 = 2 * w + i;
            bf16x8 bfr = *(const bf16x8*)(w2f + ((size_t)(nt2 * 8 + ks) * 64 + l) * 8);
            acc2[i] = __builtin_amdgcn_mfma_f32_16x16x32_bf16(a2, bfr, acc2[i], 0, 0, 0);
        }
    }
#pragma unroll
    for (int i = 0; i < 2; ++i) {
        int nt2 = 2 * w + i;
#pragma unroll
        for (int r = 0; r < 4; ++r) {
            size_t o = (size_t)(n0 + 4 * g + r) * C_DIM + nt2 * 16 + lr;
            out[o] = xt[4 * g + r][nt2 * 16 + lr] + acc2[i][r];
        }
    }
}

// ---------- atomic fallback: conv sums into xbuf (h_mod in paired layout) ----------
__global__ __launch_bounds__(256) void k_edge_atomic(
        const int* __restrict__ ei, const float* __restrict__ ea,
        const float* __restrict__ w1, const float* __restrict__ b1,
        const float* __restrict__ w2, const float* __restrict__ b2,
        const float* __restrict__ w3, const float* __restrict__ b3,
        const u16* __restrict__ h_mod, float* __restrict__ xacc, int E) {
    int e = blockIdx.x * 256 + threadIdx.x;
    if (e >= E) return;
    int src = ei[e], dst = ei[E + e];
    float ax = ea[(size_t)e * 2], ay = ea[(size_t)e * 2 + 1];
    float k1[FC];
#pragma unroll
    for (int i = 0; i < FC; ++i) k1[i] = gelu_f(ax * w1[i] + ay * w1[FC + i] + b1[i]);
    float k2v[FC];
#pragma unroll
    for (int j = 0; j < FC; ++j) {
        float acc = b2[j];
#pragma unroll
        for (int i = 0; i < FC; ++i) acc += k1[i] * w2[i * FC + j];
        k2v[j] = gelu_f(acc);
    }
    const u16* hrow = h_mod + (size_t)src * C_DIM;
    float* orow = xacc + (size_t)dst * C_DIM;
    for (int c = 0; c < C_DIM; ++c) {
        float wv = b3[c];
#pragma unroll
        for (int j = 0; j < FC; ++j) wv += k2v[j] * w3[j * C_DIM + c];
        atomicAdd(&orow[c], wv * bf2f(hrow[hperm(c)]));
    }
}

extern "C" void kernel_launch(void* const* d_in, const int* in_sizes, int n_in,
                              void* d_out, int out_size, void* d_ws, size_t ws_size,
                              hipStream_t stream) {
    const float* feats = (const float*)d_in[0];
    const int*   ei    = (const int*)d_in[1];
    const float* ea    = (const float*)d_in[2];
    const float* t     = (const float*)d_in[3];
    const float* normv = (const float*)d_in[4];
    const float* ln1s  = (const float*)d_in[5];
    const float* ln1b  = (const float*)d_in[6];
    const float* ln2s  = (const float*)d_in[7];
    const float* ln2b  = (const float*)d_in[8];
    const float* tw1   = (const float*)d_in[9];
    const float* tb1   = (const float*)d_in[10];
    const float* tw2   = (const float*)d_in[11];
    const float* tb2   = (const float*)d_in[12];
    const float* kw1   = (const float*)d_in[13];
    const float* kb1   = (const float*)d_in[14];
    const float* kw2   = (const float*)d_in[15];
    const float* kb2   = (const float*)d_in[16];
    const float* kw3   = (const float*)d_in[17];
    const float* kb3   = (const float*)d_in[18];
    const float* cbias = (const float*)d_in[19];
    const float* mw1   = (const float*)d_in[20];
    const float* mb1   = (const float*)d_in[21];
    const float* mw2   = (const float*)d_in[22];
    const float* mb2   = (const float*)d_in[23];
    float* out = (float*)d_out;

    const int N = in_sizes[0] / C_DIM;
    const int E = in_sizes[1] / 2;
    const int B = in_sizes[3] / T_DIM;
    const int q = N / B;
    const int nb = (N + 1023) / 1024;

    char* wp = (char*)d_ws;
    auto alloc = [&](size_t bytes) -> char* {
        char* p = wp; wp += (bytes + 255) & ~(size_t)255; return p;
    };
    float* tm1       = (float*)alloc((size_t)B * TWO_C * 4);
    float* tm2       = (float*)alloc((size_t)B * TWO_C * 4);
    u16*   h_mod     = (u16*)alloc(((size_t)N + 1) * C_DIM * 2);
    u16*   w1f       = (u16*)alloc((size_t)C_DIM * TWO_C * 2);
    u16*   w2f       = (u16*)alloc((size_t)TWO_C * C_DIM * 2);
    u16*   w3f       = (u16*)alloc((size_t)FC * C_DIM * 2);
    u16*   w2kf      = (u16*)alloc((size_t)FC * FC * 2);
    u16*   histB     = (u16*)alloc((size_t)HB * N * 2);
    int*   blockBase = (int*)alloc((size_t)HB * N * 4);
    u64*   bsum      = (u64*)alloc(((size_t)nb + 1) * 8);
    int*   Ttot      = (int*)alloc(256);
    int4*  tinfo     = (int4*)alloc(((size_t)E / 16 + N + 64) * 16);
    float* xbuf      = (float*)alloc((size_t)N * C_DIM * 4);
    uint2* sed2      = (uint2*)alloc(((size_t)E + 16) * 8);
    size_t fixed = (size_t)(wp - (char*)d_ws);
    bool can_sort = (ws_size >= fixed + ((size_t)E + 16) * 64) &&
                    (N <= NMAX) && ((N & 1) == 0);
    u32* k2h = (u32*)alloc(((size_t)E + 16) * 64);

    const int eb = (E + 255) / 256;

    const int nbPrep = (PREP_TOT + 255) / 256;
    const int nbXb   = (N * (C_DIM / 4) + 255) / 256;
    const int nbFront = 2 * B + nbPrep + nbXb;

    k_front<<<nbFront, 256, 0, stream>>>(t, tw1, tb1, tw2, tb2,
                                         mw1, mw2, kw3, kw2, tm1, tm2,
                                         w1f, w2f, w3f, w2kf, xbuf,
                                         N, B, nbPrep, nbXb);
    k_mod2<<<N / 2 + 1, 256, 0, stream>>>(feats, ln1s, ln1b, tm1, h_mod, q, N);

    if (can_sort) {
        k_hist_lds<<<HB, 1024, 0, stream>>>(ei + E, histB, N, E);
        k_scan_bsum<<<nb, 1024, 0, stream>>>(histB, bsum, N);
        k_scan_final<<<nb, 1024, 0, stream>>>(histB, bsum, blockBase, tinfo,
                                              Ttot, N, nb);
        k_sed2<<<HB, 1024, 0, stream>>>(ei, ea, blockBase, sed2, N, E);
        k_edgek2s<<<eb, 256, 0, stream>>>(sed2, kw1, kb1, w2kf, kb2, k2h, E);
        k_conv4<<<3072, 256, 0, stream>>>(h_mod, Ttot, (const int*)tinfo, k2h, sed2,
                                          w3f, kb3, xbuf, N);
    } else {
        k_edge_atomic<<<eb, 256, 0, stream>>>(ei, ea, kw1, kb1, kw2, kb2, kw3, kb3,
                                              h_mod, xbuf, E);
    }

    k_ffn3<<<N / 16, 256, 0, stream>>>(feats, xbuf, cbias, normv, tm2, ln2s, ln2b,
                                       w1f, mb1, w2f, mb2, out, q);
}

// Round 24
// 201.529 us; speedup vs baseline: 1.0424x; 1.0424x over previous
//
#include <hip/hip_runtime.h>
#include <hip/hip_bf16.h>

#define C_DIM 128
#define TWO_C 256
#define FC    32
#define T_DIM 512
#define HB    128
#define NMAX  32768
#define PREP_TOT (32768 + 32768 + 4096 + 1024)

typedef unsigned int   u32;
typedef unsigned short u16;
typedef unsigned long long u64;
typedef short bf16x8 __attribute__((ext_vector_type(8)));
typedef float f32x4  __attribute__((ext_vector_type(4)));

__device__ __forceinline__ float fast_rcp(float x) {
    return __builtin_amdgcn_rcpf(x);          // v_rcp_f32, ~1 ULP
}
// gelu via A&S 7.1.27 rational erf (|eps_erf| <= 5e-4), 1/sqrt2 folded into coeffs.
__device__ __forceinline__ float gelu_f(float x) {
    float a = fabsf(x);
    float p = 1.0f + a * (0.19685352f + a * (0.11519450f +
              a * (3.4364302e-4f + a * 0.019527027f)));
    float d  = fast_rcp(p);
    float d2 = d * d;
    float d4 = d2 * d2;
    float s = 0.5f * x;
    return s + s * copysignf(1.0f - d4, x);
}
__device__ __forceinline__ u32 f2bf_bits(float x) {
    u32 u = __float_as_uint(x);
    return (u + 0x7fffu + ((u >> 16) & 1u)) >> 16;   // RNE f32->bf16
}
__device__ __forceinline__ u32 pack_bf2(float lo, float hi) {
    __hip_bfloat162 p = __float22bfloat162_rn(make_float2(lo, hi));  // v_cvt_pk_bf16_f32
    u32 r; __builtin_memcpy(&r, &p, 4); return r;
}
__device__ __forceinline__ float bf2f(u16 v) {
    return __uint_as_float((u32)v << 16);
}
// paired-channel h layout: channel c -> u16 index (c>>5)*32 + (c&15)*2 + ((c>>4)&1)
__device__ __forceinline__ int hperm(int c) {
    return ((c >> 5) << 5) + ((c & 15) << 1) + ((c >> 4) & 1);
}

// ---------- k_front: grid-partitioned fusion of independent prologue work ----------
__global__ __launch_bounds__(256) void k_front(
        const float* __restrict__ t,
        const float* __restrict__ tw1, const float* __restrict__ tb1,
        const float* __restrict__ tw2, const float* __restrict__ tb2,
        const float* __restrict__ mw1, const float* __restrict__ mw2,
        const float* __restrict__ kw3, const float* __restrict__ kw2,
        float* __restrict__ tm1, float* __restrict__ tm2,
        u16* __restrict__ w1f, u16* __restrict__ w2f,
        u16* __restrict__ w3f, u16* __restrict__ w2kf,
        float* __restrict__ xbuf,
        int N, int B, int nbPrep, int nbXb) {
    int bid = blockIdx.x, tid = threadIdx.x;

    if (bid < 2 * B) {
        // ---- tmod ----
        int y = bid >= B;
        int b = y ? bid - B : bid;
        const float* twp = y ? tw2 : tw1;
        const float* tbp = y ? tb2 : tb1;
        float*       tmp = y ? tm2 : tm1;
        __shared__ float gt[T_DIM];
        for (int k = tid; k < T_DIM; k += 256)
            gt[k] = gelu_f(t[(size_t)b * T_DIM + k]);
        __syncthreads();
        float acc = tbp[tid];
        for (int k = 0; k < T_DIM; ++k)
            acc += gt[k] * twp[(size_t)k * TWO_C + tid];
        tmp[(size_t)b * TWO_C + tid] = acc;
        return;
    }
    bid -= 2 * B;

    if (bid < nbPrep) {
        int tt = bid * 256 + tid;
        if (tt < 32768) {            // w1f: [nt16][ks4][64][8], W = mw1 [128][256]
            int j = tt & 7, l = (tt >> 3) & 63, f = tt >> 9;
            int ks = f & 3, nt = f >> 2;
            int k = ks * 32 + ((l >> 4) << 3) + j, n = nt * 16 + (l & 15);
            w1f[tt] = (u16)f2bf_bits(mw1[(size_t)k * TWO_C + n]);
        } else if (tt < 65536) {     // w2f: [nt8][ks8][64][8], W = mw2 [256][128]
            int t2 = tt - 32768;
            int j = t2 & 7, l = (t2 >> 3) & 63, f = t2 >> 9;
            int ks = f & 7, nt = f >> 3;
            int k = ks * 32 + ((l >> 4) << 3) + j, n = nt * 16 + (l & 15);
            w2f[t2] = (u16)f2bf_bits(mw2[(size_t)k * C_DIM + n]);
        } else if (tt < 69632) {     // w3f: k permuted by pi
            int t3 = tt - 65536;
            int j = t3 & 7, l = (t3 >> 3) & 63, nt = t3 >> 9;
            int kk = ((l >> 4) << 3) + j;
            int k = (kk >> 1) + ((kk & 1) << 4);
            int n = nt * 16 + (l & 15);
            w3f[t3] = (u16)f2bf_bits(kw3[(size_t)k * C_DIM + n]);
        } else if (tt < PREP_TOT) {  // w2kf
            int t4 = tt - 69632;
            int j = t4 & 7, l = (t4 >> 3) & 63, nt = t4 >> 9;
            int kk = ((l >> 4) << 3) + j;
            int n = nt * 16 + (l & 15);
            w2kf[t4] = (u16)f2bf_bits(kw2[(size_t)kk * FC + n]);
        }
        return;
    }
    bid -= nbPrep;

    if (bid < nbXb) {
        size_t i = ((size_t)bid * 256 + tid) * 4;
        if (i < (size_t)N * C_DIM)
            *(float4*)(xbuf + i) = make_float4(0.f, 0.f, 0.f, 0.f);
        return;
    }
}

// ---------- k_mod2: LN1+modulate, 2 rows/block (bitwise k_mod numerics) ----------
__global__ __launch_bounds__(256) void k_mod2(
        const float* __restrict__ feats,
        const float* __restrict__ lns, const float* __restrict__ lnb,
        const float* __restrict__ tm,
        u16* __restrict__ h_mod, int q, int N) {
    __shared__ float red2[2][4];
    int tid = threadIdx.x;
    int gi = tid >> 7, c = tid & 127;
    int n = 2 * blockIdx.x + gi;
    bool live = (n < N);
    size_t o = (size_t)n * C_DIM + c;
    float v = live ? feats[o] : 0.f;           // dummy rows participate in syncs
    float s1 = v, s2 = v * v;
#pragma unroll
    for (int off = 32; off > 0; off >>= 1) {
        s1 += __shfl_down(s1, off);
        s2 += __shfl_down(s2, off);
    }
    if ((c & 63) == 0) {
        red2[gi][(c >> 6) * 2] = s1;
        red2[gi][(c >> 6) * 2 + 1] = s2;
    }
    __syncthreads();
    if (n == N) { h_mod[(size_t)N * C_DIM + c] = 0; return; }
    if (!live) return;
    float mean = (red2[gi][0] + red2[gi][2]) * (1.0f / C_DIM);
    float ex2  = (red2[gi][1] + red2[gi][3]) * (1.0f / C_DIM);
    float r    = rsqrtf(ex2 - mean * mean + 1e-5f);
    int b = n / q;
    float scale = tm[(size_t)b * TWO_C + c];
    float shift = tm[(size_t)b * TWO_C + C_DIM + c];
    float h = (v - mean) * r * lns[c] + lnb[c];
    float res = h * (1.0f + scale) + shift;
    h_mod[(size_t)n * C_DIM + hperm(c)] = (u16)f2bf_bits(res);
}

// ---------- pass 1: per-block LDS histogram (packed u16 pairs), no global atomics ----------
__global__ __launch_bounds__(1024) void k_hist_lds(const int* __restrict__ dst,
                                                   u16* __restrict__ histB,
                                                   int N, int E) {
    __shared__ u32 lh[NMAX / 2];               // 64 KB: counts for dst pairs (2i, 2i+1)
    int tid = threadIdx.x, b = blockIdx.x;
    int half = N >> 1;
    for (int i = tid; i < half; i += 1024) lh[i] = 0;
    __syncthreads();
    int e0 = (int)((size_t)b * E / HB), e1 = (int)((size_t)(b + 1) * E / HB);
    for (int e = e0 + tid; e < e1; e += 1024) {
        int d = dst[e];
        atomicAdd(&lh[d >> 1], (d & 1) ? 0x10000u : 1u);
    }
    __syncthreads();
    u16* outp = histB + (size_t)b * N;
    for (int i = tid; i < half; i += 1024) {
        u32 v = lh[i];
        outp[2 * i]     = (u16)(v & 0xffffu);
        outp[2 * i + 1] = (u16)(v >> 16);
    }
}

// ---------- scan phase A: per-block reduction over block-histogram sums ----------
__global__ __launch_bounds__(1024) void k_scan_bsum(const u16* __restrict__ histB,
                                                    u64* __restrict__ bsum, int N) {
    __shared__ u64 red[1024];
    int t = threadIdx.x;
    int idx = blockIdx.x * 1024 + t;
    int v = 0;
    if (idx < N) {
        for (int b = 0; b < HB; ++b) v += histB[(size_t)b * N + idx];
    }
    red[t] = (u64)(u32)v | ((u64)(u32)((v + 15) >> 4) << 32);
    __syncthreads();
#pragma unroll
    for (int off = 512; off > 0; off >>= 1) {
        if (t < off) red[t] += red[t + off];
        __syncthreads();
    }
    if (t == 0) bsum[blockIdx.x] = red[0];
}

// ---------- scan phase B: local scan + per-block base table + tinfo + Ttot ----------
__global__ __launch_bounds__(1024) void k_scan_final(const u16* __restrict__ histB,
                                                     const u64* __restrict__ bsum,
                                                     int* __restrict__ blockBase,
                                                     int4* __restrict__ tinfo,
                                                     int* __restrict__ Ttot,
                                                     int N, int nb) {
    __shared__ u64 tot[1024];
    __shared__ u64 bex;
    int t = threadIdx.x;
    int idx = blockIdx.x * 1024 + t;
    int v = 0;
    if (idx < N) {
        for (int b = 0; b < HB; ++b) v += histB[(size_t)b * N + idx];
    }
    u64 pk = (u64)(u32)v | ((u64)(u32)((v + 15) >> 4) << 32);
    tot[t] = pk;
    if (t == 0) {                              // serial prefix over <=32 block sums
        u64 run = 0, mine = 0;
        for (int i = 0; i < nb; ++i) {
            if (i == (int)blockIdx.x) mine = run;
            run += bsum[i];
        }
        bex = mine;
        if (blockIdx.x == 0) Ttot[0] = (int)(run >> 32);
    }
    __syncthreads();
    for (int off = 1; off < 1024; off <<= 1) {
        u64 a = (t >= off) ? tot[t - off] : 0ull;
        __syncthreads();
        tot[t] += a;
        __syncthreads();
    }
    if (idx >= N) return;
    u64 ex = tot[t] - pk + bex;                // exclusive global prefix
    int rd = (int)(ex & 0xffffffffull);
    int rt = (int)(ex >> 32);
    int run = rd;
    for (int b = 0; b < HB; ++b) {             // per-block segment bases
        blockBase[(size_t)b * N + idx] = run;
        run += histB[(size_t)b * N + idx];
    }
    int nt = (v + 15) >> 4;
    int e = rd + v;
    for (int k = 0; k < nt; ++k)
        tinfo[rt + k] = make_int4(idx, rd + 16 * k, e, 0);
}

// ---------- pass 2: rank via LDS atomic return + base load; 8B record scatter ----------
__global__ __launch_bounds__(1024) void k_sed2(const int* __restrict__ ei,
                                               const float* __restrict__ ea,
                                               const int* __restrict__ blockBase,
                                               uint2* __restrict__ sed2,
                                               int N, int E) {
    __shared__ u32 lh[NMAX / 2];               // 64 KB
    int tid = threadIdx.x, b = blockIdx.x;
    int half = N >> 1;
    for (int i = tid; i < half; i += 1024) lh[i] = 0;
    __syncthreads();
    int e0 = (int)((size_t)b * E / HB), e1 = (int)((size_t)(b + 1) * E / HB);
    const int* dstp = ei + E;
    for (int e = e0 + tid; e < e1; e += 1024) {
        int d = dstp[e];
        u32 old = atomicAdd(&lh[d >> 1], (d & 1) ? 0x10000u : 1u);
        int lrank = (d & 1) ? (int)(old >> 16) : (int)(old & 0xffffu);
        int pos = blockBase[(size_t)b * N + d] + lrank;
        float2 av = ((const float2*)ea)[e];
        uint2 v;
        v.x = pack_bf2(av.x, av.y);
        v.y = (u32)ei[e];
        sed2[pos] = v;
    }
}

// ---------- edge kernel-MLP in SORTED order: dense coalesced in/out ----------
__global__ __launch_bounds__(256) void k_edgek2s(
        const uint2* __restrict__ sed2,
        const float* __restrict__ w1, const float* __restrict__ b1,
        const u16* __restrict__ w2kf, const float* __restrict__ b2,
        u32* __restrict__ k2h, int E) {
    int l = threadIdx.x & 63, wv = threadIdx.x >> 6;
    int lr = l & 15, g = l >> 4;
    int wbase = blockIdx.x * 256 + wv * 64;

    bf16x8 wb0 = *(const bf16x8*)(w2kf + (size_t)l * 8);
    bf16x8 wb1 = *(const bf16x8*)(w2kf + (size_t)(64 + l) * 8);
    f32x4 bi0, bi1;
    {
        float v0 = b2[lr], v1 = b2[16 + lr];
        bi0[0] = v0; bi0[1] = v0; bi0[2] = v0; bi0[3] = v0;
        bi1[0] = v1; bi1[1] = v1; bi1[2] = v1; bi1[3] = v1;
    }
    float w1x[8], w1y[8], b1v[8];
#pragma unroll
    for (int j = 0; j < 8; ++j) {
        w1x[j] = w1[8 * g + j];
        w1y[j] = w1[FC + 8 * g + j];
        b1v[j] = b1[8 * g + j];
    }
#pragma unroll
    for (int c = 0; c < 4; ++c) {
        int cb = wbase + 16 * c;
        int pA = cb + lr;
        float ax = 0.f, ay = 0.f;
        if (pA < E) {
            u32 pr = sed2[pA].x;
            ax = bf2f((u16)(pr & 0xffffu));
            ay = bf2f((u16)(pr >> 16));
        }
        union { u32 w[4]; bf16x8 v; } au;
#pragma unroll
        for (int m = 0; m < 4; ++m) {
            float v0 = gelu_f(fmaf(ax, w1x[2 * m],     fmaf(ay, w1y[2 * m],     b1v[2 * m])));
            float v1 = gelu_f(fmaf(ax, w1x[2 * m + 1], fmaf(ay, w1y[2 * m + 1], b1v[2 * m + 1])));
            au.w[m] = pack_bf2(v0, v1);
        }
        f32x4 d0 = __builtin_amdgcn_mfma_f32_16x16x32_bf16(au.v, wb0, bi0, 0, 0, 0);
        f32x4 d1 = __builtin_amdgcn_mfma_f32_16x16x32_bf16(au.v, wb1, bi1, 0, 0, 0);
#pragma unroll
        for (int r = 0; r < 4; ++r) {
            int pD = cb + 4 * g + r;
            if (pD < E) {
                u32 pk = pack_bf2(gelu_f(d0[r]), gelu_f(d1[r]));
                k2h[(size_t)pD * 16 + lr] = pk;
            }
        }
    }
}

// ---------- conv main (R12/R15/R21-proven config): tile-parallel, grid-stride ----------
__global__ __launch_bounds__(256, 5) void k_conv4(
        const u16* __restrict__ h_mod,        // (N+1) rows bf16 paired, row N = zeros
        const int* __restrict__ Ttot,
        const int4* __restrict__ tinfo,       // {node, p0, end, 0}
        const u32* __restrict__ k2h,          // [E][16] u32, dense sorted
        const uint2* __restrict__ sed2,       // {bf16pair, src}
        const u16* __restrict__ w3f, const float* __restrict__ kb3,
        float* __restrict__ xbuf, int N) {
    int l = threadIdx.x & 63, wv = threadIdx.x >> 6;
    int lr = l & 15, g = l >> 4;

    bf16x8 w3b[8];
#pragma unroll
    for (int nt = 0; nt < 8; ++nt)
        w3b[nt] = *(const bf16x8*)(w3f + ((size_t)nt * 64 + l) * 8);
    float b3c[8];
#pragma unroll
    for (int nt = 0; nt < 8; ++nt) b3c[nt] = kb3[nt * 16 + lr];
    const f32x4 zc = {0.f, 0.f, 0.f, 0.f};
    const u32* h32 = (const u32*)h_mod;

    int T = Ttot[0];
    int nw = gridDim.x * 4;
#pragma unroll 1
    for (int t = blockIdx.x * 4 + wv; t < T; t += nw) {
        int4 ti = tinfo[t];
        int n = ti.x, p0 = ti.y, e = ti.z;
        int pa = p0 + lr;
        bf16x8 a = {0, 0, 0, 0, 0, 0, 0, 0};
        if (pa < e) a = *(const bf16x8*)(k2h + (size_t)pa * 16 + g * 4);
        int srcv[4];
#pragma unroll
        for (int r = 0; r < 4; ++r) {
            int pp = p0 + 4 * g + r;
            srcv[r] = (pp < e) ? (int)sed2[pp].y : N;
        }
        const u32* h0p = h32 + (size_t)srcv[0] * 64 + lr;
        const u32* h1p = h32 + (size_t)srcv[1] * 64 + lr;
        const u32* h2p = h32 + (size_t)srcv[2] * 64 + lr;
        const u32* h3p = h32 + (size_t)srcv[3] * 64 + lr;
        float acc[8];
#pragma unroll
        for (int j = 0; j < 4; ++j) {
            f32x4 w0 = __builtin_amdgcn_mfma_f32_16x16x32_bf16(a, w3b[2 * j],     zc, 0, 0, 0);
            f32x4 w1 = __builtin_amdgcn_mfma_f32_16x16x32_bf16(a, w3b[2 * j + 1], zc, 0, 0, 0);
            u32 u0 = h0p[j * 16], u1 = h1p[j * 16], u2 = h2p[j * 16], u3 = h3p[j * 16];
            float l0 = __uint_as_float(u0 << 16), h0 = __uint_as_float(u0 & 0xffff0000u);
            float l1 = __uint_as_float(u1 << 16), h1 = __uint_as_float(u1 & 0xffff0000u);
            float l2 = __uint_as_float(u2 << 16), h2 = __uint_as_float(u2 & 0xffff0000u);
            float l3 = __uint_as_float(u3 << 16), h3 = __uint_as_float(u3 & 0xffff0000u);
            acc[2 * j]     = w0[0] * l0 + w0[1] * l1 + w0[2] * l2 + w0[3] * l3
                           + b3c[2 * j] * (l0 + l1 + l2 + l3);
            acc[2 * j + 1] = w1[0] * h0 + w1[1] * h1 + w1[2] * h2 + w1[3] * h3
                           + b3c[2 * j + 1] * (h0 + h1 + h2 + h3);
        }
#pragma unroll
        for (int nt = 0; nt < 8; ++nt) {
            acc[nt] += __shfl_xor(acc[nt], 16, 64);
            acc[nt] += __shfl_xor(acc[nt], 32, 64);
        }
        float v0 = (g == 0) ? acc[0] : (g == 1) ? acc[2] : (g == 2) ? acc[4] : acc[6];
        float v1 = (g == 0) ? acc[1] : (g == 1) ? acc[3] : (g == 2) ? acc[5] : acc[7];
        float* row = xbuf + (size_t)n * C_DIM + 32 * g + lr;
        atomicAdd(row, v0);
        atomicAdd(row + 16, v1);
    }
}

// ---------- fused FFN (phase 0 replicates k_post BITWISE, 2 rows/pass x 8) ----------
__global__ __launch_bounds__(256) void k_ffn3(const float* __restrict__ feats,
                                              const float* __restrict__ xbuf,
                                              const float* __restrict__ cbias,
                                              const float* __restrict__ normv,
                                              const float* __restrict__ tm2,
                                              const float* __restrict__ ln2s,
                                              const float* __restrict__ ln2b,
                                              const u16* __restrict__ w1f,
                                              const float* __restrict__ b1,
                                              const u16* __restrict__ w2f,
                                              const float* __restrict__ b2,
                                              float* __restrict__ out, int q) {
    __shared__ u16 xmt[2048];
    __shared__ float xt[16][128];
    __shared__ u16 sm[4096];
    __shared__ float red2[2][4];
    int tid = threadIdx.x;
    int n0 = blockIdx.x * 16;

    {
        int gi = tid >> 7, c = tid & 127;
#pragma unroll 1
        for (int it = 0; it < 8; ++it) {
            int rA = 2 * it + gi;
            int n = n0 + rA;
            size_t o = (size_t)n * C_DIM + c;
            float v = feats[o] + (xbuf[o] + cbias[c]) * fast_rcp(normv[n]);
            float s1 = v, s2 = v * v;
#pragma unroll
            for (int off = 32; off > 0; off >>= 1) {
                s1 += __shfl_down(s1, off);
                s2 += __shfl_down(s2, off);
            }
            if ((c & 63) == 0) {
                red2[gi][(c >> 6) * 2] = s1;
                red2[gi][(c >> 6) * 2 + 1] = s2;
            }
            __syncthreads();
            float mean = (red2[gi][0] + red2[gi][2]) * (1.0f / C_DIM);
            float ex2  = (red2[gi][1] + red2[gi][3]) * (1.0f / C_DIM);
            float r    = rsqrtf(ex2 - mean * mean + 1e-5f);
            int b = n / q;
            float scale = tm2[(size_t)b * TWO_C + c];
            float shift = tm2[(size_t)b * TWO_C + C_DIM + c];
            float h = (v - mean) * r * ln2s[c] + ln2b[c];
            float res = h * (1.0f + scale) + shift;
            int byte = rA * 256 + ((c * 2) ^ ((rA & 7) << 4));
            xmt[byte >> 1] = (u16)f2bf_bits(res);
            xt[rA][c] = v;
            __syncthreads();
        }
    }

    int w = tid >> 6, l = tid & 63;
    int lr = l & 15, g = l >> 4;

    bf16x8 a[4];
#pragma unroll
    for (int ks = 0; ks < 4; ++ks) {
        int byte = lr * 256 + ((ks * 64 + g * 16) ^ ((lr & 7) << 4));
        a[ks] = *(const bf16x8*)((const char*)xmt + byte);
    }
    f32x4 acc[4];
#pragma unroll
    for (int i = 0; i < 4; ++i) {
        int nt = w + 4 * i;
        float bv = b1[nt * 16 + lr];
        acc[i][0] = bv; acc[i][1] = bv; acc[i][2] = bv; acc[i][3] = bv;
#pragma unroll
        for (int ks = 0; ks < 4; ++ks) {
            bf16x8 bfr = *(const bf16x8*)(w1f + ((size_t)(nt * 4 + ks) * 64 + l) * 8);
            acc[i] = __builtin_amdgcn_mfma_f32_16x16x32_bf16(a[ks], bfr, acc[i], 0, 0, 0);
        }
    }
#pragma unroll
    for (int i = 0; i < 4; ++i) {
        int nt = w + 4 * i;
#pragma unroll
        for (int r = 0; r < 4; ++r) {
            int row = 4 * g + r, col = nt * 16 + lr;
            int byte = row * 512 + ((col * 2) ^ ((row & 7) << 4));
            sm[byte >> 1] = (u16)f2bf_bits(gelu_f(acc[i][r]));
        }
    }
    __syncthreads();
    f32x4 acc2[2];
#pragma unroll
    for (int i = 0; i < 2; ++i) {
        int nt2 = 2 * w + i;
        float bv = b2[nt2 * 16 + lr];
        acc2[i][0] = bv; acc2[i][1] = bv; acc2[i][2] = bv; acc2[i][3] = bv;
    }
#pragma unroll
    for (int ks = 0; ks < 8; ++ks) {
        int byte = lr * 512 + ((ks * 64 + g * 16) ^ ((lr & 7) << 4));
        bf16x8 a2 = *(const bf16x8*)(sm + (byte >> 1));
#pragma unroll
        for (int i = 0; i < 2; ++i) {
            int nt2 = 2 * w + i;
            bf16x8 bfr = *(const bf16x8*)(w2f + ((size_t)(nt2 * 8 + ks) * 64 + l) * 8);
            acc2[i] = __builtin_amdgcn_mfma_f32_16x16x32_bf16(a2, bfr, acc2[i], 0, 0, 0);
        }
    }
#pragma unroll
    for (int i = 0; i < 2; ++i) {
        int nt2 = 2 * w + i;
#pragma unroll
        for (int r = 0; r < 4; ++r) {
            size_t o = (size_t)(n0 + 4 * g + r) * C_DIM + nt2 * 16 + lr;
            out[o] = xt[4 * g + r][nt2 * 16 + lr] + acc2[i][r];
        }
    }
}

// ---------- atomic fallback: conv sums into xbuf (h_mod in paired layout) ----------
__global__ __launch_bounds__(256) void k_edge_atomic(
        const int* __restrict__ ei, const float* __restrict__ ea,
        const float* __restrict__ w1, const float* __restrict__ b1,
        const float* __restrict__ w2, const float* __restrict__ b2,
        const float* __restrict__ w3, const float* __restrict__ b3,
        const u16* __restrict__ h_mod, float* __restrict__ xacc, int E) {
    int e = blockIdx.x * 256 + threadIdx.x;
    if (e >= E) return;
    int src = ei[e], dst = ei[E + e];
    float ax = ea[(size_t)e * 2], ay = ea[(size_t)e * 2 + 1];
    float k1[FC];
#pragma unroll
    for (int i = 0; i < FC; ++i) k1[i] = gelu_f(ax * w1[i] + ay * w1[FC + i] + b1[i]);
    float k2v[FC];
#pragma unroll
    for (int j = 0; j < FC; ++j) {
        float acc = b2[j];
#pragma unroll
        for (int i = 0; i < FC; ++i) acc += k1[i] * w2[i * FC + j];
        k2v[j] = gelu_f(acc);
    }
    const u16* hrow = h_mod + (size_t)src * C_DIM;
    float* orow = xacc + (size_t)dst * C_DIM;
    for (int c = 0; c < C_DIM; ++c) {
        float wv = b3[c];
#pragma unroll
        for (int j = 0; j < FC; ++j) wv += k2v[j] * w3[j * C_DIM + c];
        atomicAdd(&orow[c], wv * bf2f(hrow[hperm(c)]));
    }
}

extern "C" void kernel_launch(void* const* d_in, const int* in_sizes, int n_in,
                              void* d_out, int out_size, void* d_ws, size_t ws_size,
                              hipStream_t stream) {
    const float* feats = (const float*)d_in[0];
    const int*   ei    = (const int*)d_in[1];
    const float* ea    = (const float*)d_in[2];
    const float* t     = (const float*)d_in[3];
    const float* normv = (const float*)d_in[4];
    const float* ln1s  = (const float*)d_in[5];
    const float* ln1b  = (const float*)d_in[6];
    const float* ln2s  = (const float*)d_in[7];
    const float* ln2b  = (const float*)d_in[8];
    const float* tw1   = (const float*)d_in[9];
    const float* tb1   = (const float*)d_in[10];
    const float* tw2   = (const float*)d_in[11];
    const float* tb2   = (const float*)d_in[12];
    const float* kw1   = (const float*)d_in[13];
    const float* kb1   = (const float*)d_in[14];
    const float* kw2   = (const float*)d_in[15];
    const float* kb2   = (const float*)d_in[16];
    const float* kw3   = (const float*)d_in[17];
    const float* kb3   = (const float*)d_in[18];
    const float* cbias = (const float*)d_in[19];
    const float* mw1   = (const float*)d_in[20];
    const float* mb1   = (const float*)d_in[21];
    const float* mw2   = (const float*)d_in[22];
    const float* mb2   = (const float*)d_in[23];
    float* out = (float*)d_out;

    const int N = in_sizes[0] / C_DIM;
    const int E = in_sizes[1] / 2;
    const int B = in_sizes[3] / T_DIM;
    const int q = N / B;
    const int nb = (N + 1023) / 1024;

    char* wp = (char*)d_ws;
    auto alloc = [&](size_t bytes) -> char* {
        char* p = wp; wp += (bytes + 255) & ~(size_t)255; return p;
    };
    float* tm1       = (float*)alloc((size_t)B * TWO_C * 4);
    float* tm2       = (float*)alloc((size_t)B * TWO_C * 4);
    u16*   h_mod     = (u16*)alloc(((size_t)N + 1) * C_DIM * 2);
    u16*   w1f       = (u16*)alloc((size_t)C_DIM * TWO_C * 2);
    u16*   w2f       = (u16*)alloc((size_t)TWO_C * C_DIM * 2);
    u16*   w3f       = (u16*)alloc((size_t)FC * C_DIM * 2);
    u16*   w2kf      = (u16*)alloc((size_t)FC * FC * 2);
    u16*   histB     = (u16*)alloc((size_t)HB * N * 2);
    int*   blockBase = (int*)alloc((size_t)HB * N * 4);
    u64*   bsum      = (u64*)alloc(((size_t)nb + 1) * 8);
    int*   Ttot      = (int*)alloc(256);
    int4*  tinfo     = (int4*)alloc(((size_t)E / 16 + N + 64) * 16);
    float* xbuf      = (float*)alloc((size_t)N * C_DIM * 4);
    uint2* sed2      = (uint2*)alloc(((size_t)E + 16) * 8);
    size_t fixed = (size_t)(wp - (char*)d_ws);
    bool can_sort = (ws_size >= fixed + ((size_t)E + 16) * 64) &&
                    (N <= NMAX) && ((N & 1) == 0);
    u32* k2h = (u32*)alloc(((size_t)E + 16) * 64);

    const int eb = (E + 255) / 256;

    const int nbPrep = (PREP_TOT + 255) / 256;
    const int nbXb   = (N * (C_DIM / 4) + 255) / 256;
    const int nbFront = 2 * B + nbPrep + nbXb;

    k_front<<<nbFront, 256, 0, stream>>>(t, tw1, tb1, tw2, tb2,
                                         mw1, mw2, kw3, kw2, tm1, tm2,
                                         w1f, w2f, w3f, w2kf, xbuf,
                                         N, B, nbPrep, nbXb);
    k_mod2<<<N / 2 + 1, 256, 0, stream>>>(feats, ln1s, ln1b, tm1, h_mod, q, N);

    if (can_sort) {
        k_hist_lds<<<HB, 1024, 0, stream>>>(ei + E, histB, N, E);
        k_scan_bsum<<<nb, 1024, 0, stream>>>(histB, bsum, N);
        k_scan_final<<<nb, 1024, 0, stream>>>(histB, bsum, blockBase, tinfo,
                                              Ttot, N, nb);
        k_sed2<<<HB, 1024, 0, stream>>>(ei, ea, blockBase, sed2, N, E);
        k_edgek2s<<<eb, 256, 0, stream>>>(sed2, kw1, kb1, w2kf, kb2, k2h, E);
        k_conv4<<<3072, 256, 0, stream>>>(h_mod, Ttot, tinfo, k2h, sed2,
                                          w3f, kb3, xbuf, N);
    } else {
        k_edge_atomic<<<eb, 256, 0, stream>>>(ei, ea, kw1, kb1, kw2, kb2, kw3, kb3,
                                              h_mod, xbuf, E);
    }

    k_ffn3<<<N / 16, 256, 0, stream>>>(feats, xbuf, cbias, normv, tm2, ln2s, ln2b,
                                       w1f, mb1, w2f, mb2, out, q);
}